// Round 5
// baseline (345.726 us; speedup 1.0000x reference)
//
#include <hip/hip_runtime.h>
#include <cmath>

// CP_LIF forward: spikes = scan over T of LIF recurrence.
//   v   = alpha*v + (1-alpha)*x_t        (f32, NO fma contraction -> match np/jax)
//   s   = (v - 1 > 0) ? 1 : 0            (forward of surrogate == hard step)
//   v  -= s * r                          (exact f32 subtract when s==1)
// Memory-bound streaming: 210 MB read + 210 MB write -> 66.7 us floor @6.29 TB/s.
//
// R4: max-occupancy variant. One neuron per thread (524288 threads, 2048
// blocks of 256 -> 32 waves/CU, the hardware cap; was 16). More independent
// load/store streams per CU for the memory controller to reorder across.
// Keep 4-deep statically-indexed register prefetch + nontemporal access.
// Numerics identical to R0/R3 (absmax was 0 both rounds).

#define TSTEPS 100
#define PF 4   // prefetch depth; (TSTEPS - PF) % PF == 0

__device__ __forceinline__ float softplus_once(float xr) {
  // true softplus rounded once to f32 (<=0.5 ulp from exact)
  double x = (double)xr;
  double sp = (x > 0.0) ? (x + log1p(exp(-x))) : log1p(exp(x));
  return (float)sp;
}

__global__ __launch_bounds__(256) void lif_fwd(
    const float* __restrict__ x,
    const float* __restrict__ tau_raw,
    const float* __restrict__ r_raw,
    float* __restrict__ out,
    int B, int N) {
#pragma clang fp contract(off)
  const int tid = blockIdx.x * blockDim.x + threadIdx.x;
  if (tid >= B * N) return;
  const int n = tid % N;    // neuron (lane-consecutive -> coalesced)

  // ---- per-neuron params (prologue, off critical path) ----
  float a, o, r;
  {
    float tau = softplus_once(tau_raw[n]) + 0.001f;
    a = (float)exp((double)(-1.0f / tau));   // f32 div (as jax -DT/tau), CR exp
    o = 1.0f - a;                            // exact (alpha in (0,1))
    r = softplus_once(r_raw[n]) + 1e-6f;
  }

  const size_t str = (size_t)B * (size_t)N;  // element stride per t
  const float* xp = x + tid;
  float*       op = out + tid;

  float v = 0.f;

  // ---- 4-deep register prefetch pipeline, all indices static ----
  float buf[PF];
#pragma unroll
  for (int j = 0; j < PF; ++j)
    buf[j] = __builtin_nontemporal_load(xp + (size_t)j * str);
  const float* xl = xp + (size_t)PF * str;

#define LIF_STEP(c)                                             \
  {                                                             \
    float vn = a * v + o * (c);    /* mul,mul,add: no fma */    \
    float u  = vn - 1.0f;                                       \
    bool fire = u > 0.0f;                                       \
    float s  = fire ? 1.0f : 0.0f;                              \
    v = fire ? (vn - r) : vn;                                   \
    __builtin_nontemporal_store(s, op);                         \
    op += str;                                                  \
  }

  // main loop: (TSTEPS-PF)/PF blocks of PF, unconditional prefetch
  for (int t = 0; t < TSTEPS - PF; t += PF) {
#pragma unroll
    for (int j = 0; j < PF; ++j) {
      float c = buf[j];
      buf[j] = __builtin_nontemporal_load(xl);
      xl += str;
      LIF_STEP(c)
    }
  }
  // tail: last PF timesteps, no loads
#pragma unroll
  for (int j = 0; j < PF; ++j) {
    float c = buf[j];
    LIF_STEP(c)
  }
#undef LIF_STEP
}

extern "C" void kernel_launch(void* const* d_in, const int* in_sizes, int n_in,
                              void* d_out, int out_size, void* d_ws, size_t ws_size,
                              hipStream_t stream) {
  const float* x       = (const float*)d_in[0];
  const float* tau_raw = (const float*)d_in[1];
  const float* r_raw   = (const float*)d_in[2];
  float*       out     = (float*)d_out;

  const int N = in_sizes[1];                    // 4096
  const int B = in_sizes[0] / (TSTEPS * N);     // 128

  const int threads = B * N;                    // 524288
  if (threads <= 0) return;
  const int block   = 256;
  const int grid    = (threads + block - 1) / block;  // 2048
  lif_fwd<<<grid, block, 0, stream>>>(x, tau_raw, r_raw, out, B, N);
}

// Round 6
// 338.415 us; speedup vs baseline: 1.0216x; 1.0216x over previous
//
#include <hip/hip_runtime.h>
#include <cmath>

// CP_LIF forward: spikes = scan over T of LIF recurrence.
//   v   = alpha*v + (1-alpha)*x_t        (f32, NO fma contraction -> match np/jax)
//   s   = (v - 1 > 0) ? 1 : 0            (forward of surrogate == hard step)
//   v  -= s * r                          (exact f32 subtract when s==1)
// Memory-bound streaming: 210 MB read + 210 MB write -> 66.7 us floor @6.29 TB/s.
//
// R5 == R3 (best measured: 338.7 us bench; scalar R4 regressed to 345.7).
// float2/thread (16 waves/CU), 4-deep statically-indexed register prefetch,
// nontemporal load/store. Numerics: no-contract recurrence + double-rounded
// params -> absmax 0 in R1/R3/R4.

#define TSTEPS 100
#define PF 4   // prefetch depth

typedef float f32x2 __attribute__((ext_vector_type(2)));

__device__ __forceinline__ float softplus_once(float xr) {
  // true softplus rounded once to f32 (<=0.5 ulp from exact)
  double x = (double)xr;
  double sp = (x > 0.0) ? (x + log1p(exp(-x))) : log1p(exp(x));
  return (float)sp;
}

__global__ __launch_bounds__(256) void lif_fwd(
    const float* __restrict__ x,
    const float* __restrict__ tau_raw,
    const float* __restrict__ r_raw,
    float* __restrict__ out,
    int B, int N) {
#pragma clang fp contract(off)
  const int nh  = N >> 1;                        // float2 groups per row
  const int tid = blockIdx.x * blockDim.x + threadIdx.x;
  if (tid >= B * nh) return;
  const int n0 = (tid % nh) << 1;                // first neuron of this pair
  const int b  = tid / nh;

  // ---- per-neuron params (prologue, off critical path) ----
  float a0, a1, o0, o1, r0, r1;
  {
    float tau = softplus_once(tau_raw[n0]) + 0.001f;
    a0 = (float)exp((double)(-1.0f / tau));      // f32 div, then CR exp
    o0 = 1.0f - a0;
    r0 = softplus_once(r_raw[n0]) + 1e-6f;
    tau = softplus_once(tau_raw[n0 + 1]) + 0.001f;
    a1 = (float)exp((double)(-1.0f / tau));
    o1 = 1.0f - a1;
    r1 = softplus_once(r_raw[n0 + 1]) + 1e-6f;
  }

  const size_t base2 = ((size_t)b * (size_t)N + (size_t)n0) >> 1;
  const size_t str2  = ((size_t)B * (size_t)N) >> 1;   // f32x2 stride per t
  const f32x2* xp = (const f32x2*)x + base2;
  f32x2*       op = (f32x2*)out + base2;

  float v0 = 0.f, v1 = 0.f;

  // ---- 4-deep register prefetch pipeline, all indices static ----
  f32x2 buf[PF];
#pragma unroll
  for (int j = 0; j < PF; ++j)
    buf[j] = __builtin_nontemporal_load(&xp[(size_t)j * str2]);
  const f32x2* xl = xp + (size_t)PF * str2;

#define LIF_STEP(c)                                               \
  {                                                               \
    f32x2 s;                                                      \
    {                                                             \
      float vn = a0 * v0 + o0 * (c)[0];  /* mul,mul,add: no fma */\
      float u  = vn - 1.0f;                                       \
      bool fire = u > 0.0f;                                       \
      s[0] = fire ? 1.0f : 0.0f;                                  \
      v0   = fire ? (vn - r0) : vn;                               \
    }                                                             \
    {                                                             \
      float vn = a1 * v1 + o1 * (c)[1];                           \
      float u  = vn - 1.0f;                                       \
      bool fire = u > 0.0f;                                       \
      s[1] = fire ? 1.0f : 0.0f;                                  \
      v1   = fire ? (vn - r1) : vn;                               \
    }                                                             \
    __builtin_nontemporal_store(s, op);                           \
    op += str2;                                                   \
  }

  // main loop: TSTEPS-PF iterations, unconditional prefetch
  for (int t = 0; t < TSTEPS - PF; t += PF) {
#pragma unroll
    for (int j = 0; j < PF; ++j) {
      f32x2 c = buf[j];
      buf[j] = __builtin_nontemporal_load(xl);
      xl += str2;
      LIF_STEP(c)
    }
  }
  // tail: last PF timesteps, no loads
#pragma unroll
  for (int j = 0; j < PF; ++j) {
    f32x2 c = buf[j];
    LIF_STEP(c)
  }
#undef LIF_STEP
}

extern "C" void kernel_launch(void* const* d_in, const int* in_sizes, int n_in,
                              void* d_out, int out_size, void* d_ws, size_t ws_size,
                              hipStream_t stream) {
  const float* x       = (const float*)d_in[0];
  const float* tau_raw = (const float*)d_in[1];
  const float* r_raw   = (const float*)d_in[2];
  float*       out     = (float*)d_out;

  const int N = in_sizes[1];                    // 4096
  const int B = in_sizes[0] / (TSTEPS * N);     // 128

  const int threads = B * (N >> 1);             // 262144
  if (threads <= 0) return;
  const int block   = 256;
  const int grid    = (threads + block - 1) / block;  // 1024
  lif_fwd<<<grid, block, 0, stream>>>(x, tau_raw, r_raw, out, B, N);
}